// Round 1
// baseline (5711.690 us; speedup 1.0000x reference)
//
#include <hip/hip_runtime.h>
#include <math.h>

#define NODES   100000
#define EDGES   1600000
#define NGRAPH  64
#define DIN     128
#define DH      64
#define NLAYERS 12
#define NCOLS   ((NLAYERS + 1) * DH)   // 832
#define SSPLIT  16
#define PROP_BLOCKS 1024
#define SCHUNK  ((NODES + 1023) / 1024)  // 98

// ---------------- init ----------------
__global__ void zero_init(int* __restrict__ deg, int* __restrict__ gstart,
                          int* __restrict__ gend) {
    int i = blockIdx.x * blockDim.x + threadIdx.x;
    if (i < NODES) deg[i] = 0;
    if (i < NGRAPH) { gstart[i] = NODES; gend[i] = 0; }
}

__global__ void deg_kernel(const int* __restrict__ dst, int* __restrict__ deg) {
    int e = blockIdx.x * blockDim.x + threadIdx.x;
    if (e < EDGES) atomicAdd(&deg[dst[e]], 1);
}

__global__ void range_kernel(const int* __restrict__ batch, int* __restrict__ gstart,
                             int* __restrict__ gend) {
    int n = blockIdx.x * blockDim.x + threadIdx.x;
    if (n < NODES) {
        int b = batch[n];
        atomicMin(&gstart[b], n);
        atomicMax(&gend[b], n + 1);
    }
}

__global__ void dinv_kernel(const int* __restrict__ deg, float* __restrict__ dinv) {
    int n = blockIdx.x * blockDim.x + threadIdx.x;
    if (n < NODES) dinv[n] = 1.0f / sqrtf((float)deg[n] + 1.0f);
}

// single-block scan of deg -> CSR offsets (exclusive), also primes cursor
__global__ void scan_kernel(const int* __restrict__ deg, int* __restrict__ offs,
                            int* __restrict__ cursor) {
    __shared__ int part[1024];
    int t = threadIdx.x;
    int begin = t * SCHUNK;
    int end = begin + SCHUNK; if (end > NODES) end = NODES;
    int s = 0;
    for (int i = begin; i < end && i < NODES; ++i) s += deg[i];
    part[t] = s;
    __syncthreads();
    for (int off = 1; off < 1024; off <<= 1) {
        int v = (t >= off) ? part[t - off] : 0;
        __syncthreads();
        part[t] += v;
        __syncthreads();
    }
    int run = (t == 0) ? 0 : part[t - 1];
    for (int i = begin; i < end && i < NODES; ++i) {
        offs[i] = run; cursor[i] = run;
        run += deg[i];
    }
    if (t == 1023) offs[NODES] = part[1023];
}

__global__ void fill_kernel(const int* __restrict__ src, const int* __restrict__ dst,
                            const float* __restrict__ dinv, int* __restrict__ cursor,
                            int* __restrict__ csr_src, float* __restrict__ csr_ew) {
    int e = blockIdx.x * blockDim.x + threadIdx.x;
    if (e < EDGES) {
        int s = src[e], d = dst[e];
        int pos = atomicAdd(&cursor[d], 1);
        csr_src[pos] = s;
        csr_ew[pos] = dinv[s] * dinv[d];
    }
}

// ---------------- GEMM (+ fused graph-LN + LeakyReLU on input) ----------------
// One wave per row; lane c owns output channel c. W column kept in registers,
// input value broadcast via readlane (__shfl with literal lane).
template <int K, bool DO_LN>
__global__ __launch_bounds__(256) void gemm_kernel(
    const float* __restrict__ in, int in_stride,
    const float* __restrict__ W, float* __restrict__ h,
    const float2* __restrict__ bp,   // per-block (sum,sumsq) partials from propagate
    const float* __restrict__ lnw, const float* __restrict__ lnb, int n_nodes) {
    const int lane = threadIdx.x & 63;
    const int wwid = threadIdx.x >> 6;
    const int wid = ((blockIdx.x * blockDim.x + threadIdx.x) >> 6);
    const int nw = (gridDim.x * blockDim.x) >> 6;

    float mean = 0.f, istd = 1.f, lw = 1.f, lb = 0.f;
    if (DO_LN) {
        // reduce the 1024 propagate-block partials (double for safety)
        double ls = 0.0, lq = 0.0;
        for (int i = threadIdx.x; i < PROP_BLOCKS; i += blockDim.x) {
            float2 v = bp[i]; ls += (double)v.x; lq += (double)v.y;
        }
        for (int o = 32; o > 0; o >>= 1) { ls += __shfl_down(ls, o); lq += __shfl_down(lq, o); }
        __shared__ double shs[4], shq[4];
        if (lane == 0) { shs[wwid] = ls; shq[wwid] = lq; }
        __syncthreads();
        double tsum = shs[0] + shs[1] + shs[2] + shs[3];
        double tsq  = shq[0] + shq[1] + shq[2] + shq[3];
        double M = (double)n_nodes * 64.0;
        double mu = tsum / M;
        double var = tsq / M - mu * mu; if (var < 0.0) var = 0.0;
        mean = (float)mu;
        istd = (float)(1.0 / (sqrt(var) + 1e-5));
        lw = lnw[lane]; lb = lnb[lane];
    }

    float Wreg[K];
#pragma unroll
    for (int k = 0; k < K; ++k) Wreg[k] = W[k * 64 + lane];

    for (int r = wid; r < n_nodes; r += nw) {
        const float* row = in + (size_t)r * in_stride;
        float acc = 0.f;
        if (K == 64) {
            float v = row[lane];
            if (DO_LN) {
                v = (v - mean) * istd * lw + lb;
                v = v > 0.f ? v : 0.01f * v;
            }
#pragma unroll
            for (int k = 0; k < 64; ++k) acc += __shfl(v, k) * Wreg[k];
        } else {
            float v0 = row[lane];
            float v1 = row[64 + lane];
#pragma unroll
            for (int k = 0; k < 64; ++k) acc += __shfl(v0, k) * Wreg[k];
#pragma unroll
            for (int k = 0; k < 64; ++k) acc += __shfl(v1, k) * Wreg[64 + k];
        }
        h[(size_t)r * 64 + lane] = acc;
    }
}

// ---------------- propagate: out = segsum(h[src]*ew) + h*dinv^2 + b ----------------
// One wave per node, lane = channel. Also emits per-block (sum,sumsq) for next LN.
__global__ __launch_bounds__(256) void prop_kernel(
    const float* __restrict__ h, const float* __restrict__ dinv,
    const int* __restrict__ offs, const int* __restrict__ csr_src,
    const float* __restrict__ csr_ew, const float* __restrict__ bias,
    float* __restrict__ out /*stride NCOLS*/, float2* __restrict__ bp, int n_nodes) {
    const int lane = threadIdx.x & 63;
    const int wwid = threadIdx.x >> 6;
    const int wid = blockIdx.x * 4 + wwid;
    const int nw = gridDim.x * 4;
    float b = bias[lane];
    float lsum = 0.f, lsq = 0.f;
    for (int n = wid; n < n_nodes; n += nw) {
        float dv = dinv[n];
        float acc = h[(size_t)n * 64 + lane] * (dv * dv) + b;
        int s0 = offs[n], s1 = offs[n + 1];
        for (int idx = s0; idx < s1; ++idx) {
            int s = csr_src[idx];
            float w = csr_ew[idx];
            acc += h[(size_t)s * 64 + lane] * w;
        }
        out[(size_t)n * NCOLS + lane] = acc;
        lsum += acc; lsq += acc * acc;
    }
    for (int o = 32; o > 0; o >>= 1) { lsum += __shfl_down(lsum, o); lsq += __shfl_down(lsq, o); }
    __shared__ float ss[4], sq[4];
    if (lane == 0) { ss[wwid] = lsum; sq[wwid] = lsq; }
    __syncthreads();
    if (threadIdx.x == 0) {
        float2 v; v.x = ss[0] + ss[1] + ss[2] + ss[3]; v.y = sq[0] + sq[1] + sq[2] + sq[3];
        bp[blockIdx.x] = v;
    }
}

// ---------------- softmax aggregation (two-stage online) ----------------
__global__ void smax_partial(const float* __restrict__ x, const int* __restrict__ gstart,
                             const int* __restrict__ gend, const float* __restrict__ tptr,
                             float* __restrict__ part) {
    int g = blockIdx.x / SSPLIT;
    int sp = blockIdx.x % SSPLIT;
    int c = threadIdx.x;  // 0..831
    float t = *tptr;
    int s0 = gstart[g], s1 = gend[g];
    if (s0 > s1) { s0 = 0; s1 = 0; }
    int cnt = s1 - s0;
    int per = (cnt + SSPLIT - 1) / SSPLIT;
    int a = s0 + sp * per;
    int bnd = a + per; if (bnd > s1) bnd = s1;
    float m = -3.4e38f, su = 0.f, ws = 0.f;
    for (int n = a; n < bnd; ++n) {
        float v = x[(size_t)n * NCOLS + c];
        float y = v * t;
        if (y > m) {
            float sc = expf(m - y);
            su *= sc; ws *= sc; m = y;
        }
        float e = expf(y - m);
        su += e; ws += e * v;
    }
    size_t o = ((size_t)g * SSPLIT + sp) * 3 * NCOLS + c;
    part[o] = m; part[o + NCOLS] = su; part[o + 2 * NCOLS] = ws;
}

__global__ void smax_combine(const float* __restrict__ part, float* __restrict__ reps) {
    int i = blockIdx.x * blockDim.x + threadIdx.x;
    if (i >= NGRAPH * NCOLS) return;
    int g = i / NCOLS, c = i % NCOLS;
    float M = -3.4e38f;
    for (int s = 0; s < SSPLIT; ++s) {
        float m = part[((size_t)g * SSPLIT + s) * 3 * NCOLS + c];
        if (m > M) M = m;
    }
    float su = 0.f, ws = 0.f;
    for (int s = 0; s < SSPLIT; ++s) {
        size_t o = ((size_t)g * SSPLIT + s) * 3 * NCOLS + c;
        float e = expf(part[o] - M);
        su += part[o + NCOLS] * e;
        ws += part[o + 2 * NCOLS] * e;
    }
    reps[i] = (su > 0.f) ? ws / su : 0.f;
}

// ---------------- launch ----------------
extern "C" void kernel_launch(void* const* d_in, const int* in_sizes, int n_in,
                              void* d_out, int out_size, void* d_ws, size_t ws_size,
                              hipStream_t stream) {
    const float* nf   = (const float*)d_in[0];
    const int*   ei   = (const int*)d_in[1];
    const int*   batch = (const int*)d_in[3];
    const float* W0   = (const float*)d_in[4];
    const float* b0   = (const float*)d_in[5];
    const float* lnw  = (const float*)d_in[6];
    const float* lnb  = (const float*)d_in[7];
    const float* Ws   = (const float*)d_in[8];
    const float* bs   = (const float*)d_in[9];
    const float* tptr = (const float*)d_in[10];

    const int* esrc = ei;
    const int* edst = ei + EDGES;

    float* reps = (float*)d_out;
    float* x = reps + (size_t)NGRAPH * NCOLS;  // x region lives directly in d_out

    char* p = (char*)d_ws;
    auto alloc = [&](size_t bytes) -> void* {
        void* r = (void*)p;
        p += (bytes + 255) & ~(size_t)255;
        return r;
    };
    int*    deg     = (int*)alloc(NODES * 4);
    int*    offs    = (int*)alloc((NODES + 1) * 4);
    int*    cursor  = (int*)alloc(NODES * 4);
    int*    gstart  = (int*)alloc(NGRAPH * 4);
    int*    gend    = (int*)alloc(NGRAPH * 4);
    float*  dinv    = (float*)alloc(NODES * 4);
    int*    csr_src = (int*)alloc(EDGES * 4);
    float*  csr_ew  = (float*)alloc(EDGES * 4);
    float*  h       = (float*)alloc((size_t)NODES * DH * 4);
    float2* bp      = (float2*)alloc((size_t)(NLAYERS + 1) * PROP_BLOCKS * sizeof(float2));
    float*  part    = (float*)alloc((size_t)NGRAPH * SSPLIT * 3 * NCOLS * 4);

    zero_init<<<(NODES + 255) / 256, 256, 0, stream>>>(deg, gstart, gend);
    deg_kernel<<<(EDGES + 255) / 256, 256, 0, stream>>>(edst, deg);
    range_kernel<<<(NODES + 255) / 256, 256, 0, stream>>>(batch, gstart, gend);
    dinv_kernel<<<(NODES + 255) / 256, 256, 0, stream>>>(deg, dinv);
    scan_kernel<<<1, 1024, 0, stream>>>(deg, offs, cursor);
    fill_kernel<<<(EDGES + 255) / 256, 256, 0, stream>>>(esrc, edst, dinv, cursor, csr_src, csr_ew);

    // layer 0: h = nf @ W0 ; out0 = propagate(h) -> x[:, 0:64], stats -> bp[0]
    gemm_kernel<DIN, false><<<512, 256, 0, stream>>>(nf, DIN, W0, h, nullptr, nullptr, nullptr, NODES);
    prop_kernel<<<PROP_BLOCKS, 256, 0, stream>>>(h, dinv, offs, csr_src, csr_ew, b0,
                                                 x, bp, NODES);
    for (int i = 0; i < NLAYERS; ++i) {
        // input = LN(x[:, i*64:(i+1)*64]) via bp[i], then leaky-relu, @ Ws[i]
        gemm_kernel<DH, true><<<512, 256, 0, stream>>>(
            x + (size_t)i * DH, NCOLS, Ws + (size_t)i * DH * DH, h,
            bp + (size_t)i * PROP_BLOCKS, lnw + (size_t)i * DH, lnb + (size_t)i * DH, NODES);
        prop_kernel<<<PROP_BLOCKS, 256, 0, stream>>>(
            h, dinv, offs, csr_src, csr_ew, bs + (size_t)i * DH,
            x + (size_t)(i + 1) * DH, bp + (size_t)(i + 1) * PROP_BLOCKS, NODES);
    }

    smax_partial<<<NGRAPH * SSPLIT, NCOLS, 0, stream>>>(x, gstart, gend, tptr, part);
    smax_combine<<<(NGRAPH * NCOLS + 255) / 256, 256, 0, stream>>>(part, reps);
}

// Round 2
// 3328.386 us; speedup vs baseline: 1.7161x; 1.7161x over previous
//
#include <hip/hip_runtime.h>
#include <math.h>

#define NODES   100000
#define EDGES   1600000
#define NGRAPH  64
#define DIN     128
#define DH      64
#define NLAYERS 12
#define NCOLS   ((NLAYERS + 1) * DH)   // 832
#define NC4     (NCOLS / 4)            // 208
#define SSPLIT  16
#define PROP_BLOCKS 1024
#define SCHUNK  ((NODES + 1023) / 1024)  // 98

// ---------------- init ----------------
__global__ void zero_init(int* __restrict__ deg, int* __restrict__ gstart,
                          int* __restrict__ gend) {
    int i = blockIdx.x * blockDim.x + threadIdx.x;
    if (i < NODES) deg[i] = 0;
    if (i < NGRAPH) { gstart[i] = NODES; gend[i] = 0; }
}

__global__ void deg_kernel(const int* __restrict__ dst, int* __restrict__ deg) {
    int e = blockIdx.x * blockDim.x + threadIdx.x;
    if (e < EDGES) atomicAdd(&deg[dst[e]], 1);
}

// batch_index is SORTED -> boundaries give ranges, no atomics.
__global__ void range_kernel(const int* __restrict__ batch, int* __restrict__ gstart,
                             int* __restrict__ gend) {
    int n = blockIdx.x * blockDim.x + threadIdx.x;
    if (n >= NODES) return;
    int b = batch[n];
    if (n == 0) {
        gstart[b] = 0;
    } else {
        int pb = batch[n - 1];
        if (pb != b) { gstart[b] = n; gend[pb] = n; }
    }
    if (n == NODES - 1) gend[b] = NODES;
}

__global__ void dinv_kernel(const int* __restrict__ deg, float* __restrict__ dinv) {
    int n = blockIdx.x * blockDim.x + threadIdx.x;
    if (n < NODES) dinv[n] = 1.0f / sqrtf((float)deg[n] + 1.0f);
}

// single-block scan of deg -> CSR offsets (exclusive), also primes cursor
__global__ void scan_kernel(const int* __restrict__ deg, int* __restrict__ offs,
                            int* __restrict__ cursor) {
    __shared__ int part[1024];
    int t = threadIdx.x;
    int begin = t * SCHUNK;
    int end = begin + SCHUNK; if (end > NODES) end = NODES;
    int s = 0;
    for (int i = begin; i < end && i < NODES; ++i) s += deg[i];
    part[t] = s;
    __syncthreads();
    for (int off = 1; off < 1024; off <<= 1) {
        int v = (t >= off) ? part[t - off] : 0;
        __syncthreads();
        part[t] += v;
        __syncthreads();
    }
    int run = (t == 0) ? 0 : part[t - 1];
    for (int i = begin; i < end && i < NODES; ++i) {
        offs[i] = run; cursor[i] = run;
        run += deg[i];
    }
    if (t == 1023) offs[NODES] = part[1023];
}

__global__ void fill_kernel(const int* __restrict__ src, const int* __restrict__ dst,
                            const float* __restrict__ dinv, int* __restrict__ cursor,
                            int* __restrict__ csr_src, float* __restrict__ csr_ew) {
    int e = blockIdx.x * blockDim.x + threadIdx.x;
    if (e < EDGES) {
        int s = src[e], d = dst[e];
        int pos = atomicAdd(&cursor[d], 1);
        csr_src[pos] = s;
        csr_ew[pos] = dinv[s] * dinv[d];
    }
}

// ---------------- GEMM (+ fused graph-LN + LeakyReLU on input) ----------------
template <int K, bool DO_LN>
__global__ __launch_bounds__(256) void gemm_kernel(
    const float* __restrict__ in, int in_stride,
    const float* __restrict__ W, float* __restrict__ h,
    const float2* __restrict__ bp,
    const float* __restrict__ lnw, const float* __restrict__ lnb, int n_nodes) {
    const int lane = threadIdx.x & 63;
    const int wwid = threadIdx.x >> 6;
    const int wid = ((blockIdx.x * blockDim.x + threadIdx.x) >> 6);
    const int nw = (gridDim.x * blockDim.x) >> 6;

    float mean = 0.f, istd = 1.f, lw = 1.f, lb = 0.f;
    if (DO_LN) {
        double ls = 0.0, lq = 0.0;
        for (int i = threadIdx.x; i < PROP_BLOCKS; i += blockDim.x) {
            float2 v = bp[i]; ls += (double)v.x; lq += (double)v.y;
        }
        for (int o = 32; o > 0; o >>= 1) { ls += __shfl_down(ls, o); lq += __shfl_down(lq, o); }
        __shared__ double shs[4], shq[4];
        if (lane == 0) { shs[wwid] = ls; shq[wwid] = lq; }
        __syncthreads();
        double tsum = shs[0] + shs[1] + shs[2] + shs[3];
        double tsq  = shq[0] + shq[1] + shq[2] + shq[3];
        double M = (double)n_nodes * 64.0;
        double mu = tsum / M;
        double var = tsq / M - mu * mu; if (var < 0.0) var = 0.0;
        mean = (float)mu;
        istd = (float)(1.0 / (sqrt(var) + 1e-5));
        lw = lnw[lane]; lb = lnb[lane];
    }

    float Wreg[K];
#pragma unroll
    for (int k = 0; k < K; ++k) Wreg[k] = W[k * 64 + lane];

    for (int r = wid; r < n_nodes; r += nw) {
        const float* row = in + (size_t)r * in_stride;
        float acc = 0.f;
        if (K == 64) {
            float v = row[lane];
            if (DO_LN) {
                v = (v - mean) * istd * lw + lb;
                v = v > 0.f ? v : 0.01f * v;
            }
#pragma unroll
            for (int k = 0; k < 64; ++k) acc += __shfl(v, k) * Wreg[k];
        } else {
            float v0 = row[lane];
            float v1 = row[64 + lane];
#pragma unroll
            for (int k = 0; k < 64; ++k) acc += __shfl(v0, k) * Wreg[k];
#pragma unroll
            for (int k = 0; k < 64; ++k) acc += __shfl(v1, k) * Wreg[64 + k];
        }
        h[(size_t)r * 64 + lane] = acc;
    }
}

// ---------------- propagate: out = segsum(h[src]*ew) + h*dinv^2 + b ----------------
// 16 lanes per node (float4 channels) -> 4 nodes in flight per wave for MLP.
__global__ __launch_bounds__(256) void prop_kernel(
    const float4* __restrict__ h4, const float* __restrict__ dinv,
    const int* __restrict__ offs, const int* __restrict__ csr_src,
    const float* __restrict__ csr_ew, const float* __restrict__ bias,
    float* __restrict__ out /*stride NCOLS*/, float2* __restrict__ bp, int n_nodes) {
    const int lane = threadIdx.x & 63;
    const int sub  = lane & 15;      // channel group (4 channels)
    const int nsub = lane >> 4;      // node slot within wave
    const int wwid = threadIdx.x >> 6;
    const int wid = blockIdx.x * 4 + wwid;
    const int nw = gridDim.x * 4;
    float4 b4 = ((const float4*)bias)[sub];
    float lsum = 0.f, lsq = 0.f;
    for (int base = wid * 4; base < n_nodes; base += nw * 4) {
        int n = base + nsub;
        if (n < n_nodes) {
            float dv = dinv[n];
            float dw = dv * dv;
            float4 hv = h4[(size_t)n * 16 + sub];
            float4 acc;
            acc.x = hv.x * dw + b4.x;
            acc.y = hv.y * dw + b4.y;
            acc.z = hv.z * dw + b4.z;
            acc.w = hv.w * dw + b4.w;
            int s0 = offs[n], s1 = offs[n + 1];
            for (int idx = s0; idx < s1; ++idx) {
                int s = csr_src[idx];
                float w = csr_ew[idx];
                float4 v = h4[(size_t)s * 16 + sub];
                acc.x += v.x * w;
                acc.y += v.y * w;
                acc.z += v.z * w;
                acc.w += v.w * w;
            }
            ((float4*)(out + (size_t)n * NCOLS))[sub] = acc;
            lsum += acc.x + acc.y + acc.z + acc.w;
            lsq  += acc.x * acc.x + acc.y * acc.y + acc.z * acc.z + acc.w * acc.w;
        }
    }
    for (int o = 32; o > 0; o >>= 1) { lsum += __shfl_down(lsum, o); lsq += __shfl_down(lsq, o); }
    __shared__ float ss[4], sq[4];
    if (lane == 0) { ss[wwid] = lsum; sq[wwid] = lsq; }
    __syncthreads();
    if (threadIdx.x == 0) {
        float2 v; v.x = ss[0] + ss[1] + ss[2] + ss[3]; v.y = sq[0] + sq[1] + sq[2] + sq[3];
        bp[blockIdx.x] = v;
    }
}

// ---------------- softmax aggregation (two-stage online, float4) ----------------
#define ONLINE(comp)                                                     \
    {                                                                    \
        float y = v.comp * t;                                            \
        if (y > m.comp) {                                                \
            float sc = expf(m.comp - y);                                 \
            su.comp *= sc; ws.comp *= sc; m.comp = y;                    \
        }                                                                \
        float e = expf(y - m.comp);                                      \
        su.comp += e; ws.comp += e * v.comp;                             \
    }

__global__ __launch_bounds__(256) void smax_partial(
    const float4* __restrict__ x4, const int* __restrict__ gstart,
    const int* __restrict__ gend, const float* __restrict__ tptr,
    float* __restrict__ part) {
    int g = blockIdx.x / SSPLIT;
    int sp = blockIdx.x % SSPLIT;
    int c = threadIdx.x;           // float4 column group 0..207
    if (c >= NC4) return;
    float t = *tptr;
    int s0 = gstart[g], s1 = gend[g];
    if (s0 > s1) { s0 = 0; s1 = 0; }
    int cnt = s1 - s0;
    int per = (cnt + SSPLIT - 1) / SSPLIT;
    int a = s0 + sp * per;
    int bnd = a + per; if (bnd > s1) bnd = s1;
    float4 m  = make_float4(-3.4e38f, -3.4e38f, -3.4e38f, -3.4e38f);
    float4 su = make_float4(0.f, 0.f, 0.f, 0.f);
    float4 ws = make_float4(0.f, 0.f, 0.f, 0.f);
    for (int n = a; n < bnd; ++n) {
        float4 v = x4[(size_t)n * NC4 + c];
        ONLINE(x) ONLINE(y) ONLINE(z) ONLINE(w)
    }
    size_t base = ((size_t)g * SSPLIT + sp) * 3 * NCOLS;
    ((float4*)(part + base))[c] = m;
    ((float4*)(part + base + NCOLS))[c] = su;
    ((float4*)(part + base + 2 * NCOLS))[c] = ws;
}

__global__ void smax_combine(const float* __restrict__ part, float* __restrict__ reps) {
    int i = blockIdx.x * blockDim.x + threadIdx.x;
    if (i >= NGRAPH * NCOLS) return;
    int g = i / NCOLS, c = i % NCOLS;
    float M = -3.4e38f;
    for (int s = 0; s < SSPLIT; ++s) {
        float m = part[((size_t)g * SSPLIT + s) * 3 * NCOLS + c];
        if (m > M) M = m;
    }
    float su = 0.f, ws = 0.f;
    for (int s = 0; s < SSPLIT; ++s) {
        size_t o = ((size_t)g * SSPLIT + s) * 3 * NCOLS + c;
        float e = expf(part[o] - M);
        su += part[o + NCOLS] * e;
        ws += part[o + 2 * NCOLS] * e;
    }
    reps[i] = (su > 0.f) ? ws / su : 0.f;
}

// ---------------- launch ----------------
extern "C" void kernel_launch(void* const* d_in, const int* in_sizes, int n_in,
                              void* d_out, int out_size, void* d_ws, size_t ws_size,
                              hipStream_t stream) {
    const float* nf   = (const float*)d_in[0];
    const int*   ei   = (const int*)d_in[1];
    const int*   batch = (const int*)d_in[3];
    const float* W0   = (const float*)d_in[4];
    const float* b0   = (const float*)d_in[5];
    const float* lnw  = (const float*)d_in[6];
    const float* lnb  = (const float*)d_in[7];
    const float* Ws   = (const float*)d_in[8];
    const float* bs   = (const float*)d_in[9];
    const float* tptr = (const float*)d_in[10];

    const int* esrc = ei;
    const int* edst = ei + EDGES;

    float* reps = (float*)d_out;
    float* x = reps + (size_t)NGRAPH * NCOLS;  // x region lives directly in d_out

    char* p = (char*)d_ws;
    auto alloc = [&](size_t bytes) -> void* {
        void* r = (void*)p;
        p += (bytes + 255) & ~(size_t)255;
        return r;
    };
    int*    deg     = (int*)alloc(NODES * 4);
    int*    offs    = (int*)alloc((NODES + 1) * 4);
    int*    cursor  = (int*)alloc(NODES * 4);
    int*    gstart  = (int*)alloc(NGRAPH * 4);
    int*    gend    = (int*)alloc(NGRAPH * 4);
    float*  dinv    = (float*)alloc(NODES * 4);
    int*    csr_src = (int*)alloc(EDGES * 4);
    float*  csr_ew  = (float*)alloc(EDGES * 4);
    float*  h       = (float*)alloc((size_t)NODES * DH * 4);
    float2* bp      = (float2*)alloc((size_t)(NLAYERS + 1) * PROP_BLOCKS * sizeof(float2));
    float*  part    = (float*)alloc((size_t)NGRAPH * SSPLIT * 3 * NCOLS * 4);

    zero_init<<<(NODES + 255) / 256, 256, 0, stream>>>(deg, gstart, gend);
    deg_kernel<<<(EDGES + 255) / 256, 256, 0, stream>>>(edst, deg);
    range_kernel<<<(NODES + 255) / 256, 256, 0, stream>>>(batch, gstart, gend);
    dinv_kernel<<<(NODES + 255) / 256, 256, 0, stream>>>(deg, dinv);
    scan_kernel<<<1, 1024, 0, stream>>>(deg, offs, cursor);
    fill_kernel<<<(EDGES + 255) / 256, 256, 0, stream>>>(esrc, edst, dinv, cursor, csr_src, csr_ew);

    gemm_kernel<DIN, false><<<512, 256, 0, stream>>>(nf, DIN, W0, h, nullptr, nullptr, nullptr, NODES);
    prop_kernel<<<PROP_BLOCKS, 256, 0, stream>>>((const float4*)h, dinv, offs, csr_src, csr_ew, b0,
                                                 x, bp, NODES);
    for (int i = 0; i < NLAYERS; ++i) {
        gemm_kernel<DH, true><<<512, 256, 0, stream>>>(
            x + (size_t)i * DH, NCOLS, Ws + (size_t)i * DH * DH, h,
            bp + (size_t)i * PROP_BLOCKS, lnw + (size_t)i * DH, lnb + (size_t)i * DH, NODES);
        prop_kernel<<<PROP_BLOCKS, 256, 0, stream>>>(
            (const float4*)h, dinv, offs, csr_src, csr_ew, bs + (size_t)i * DH,
            x + (size_t)(i + 1) * DH, bp + (size_t)(i + 1) * PROP_BLOCKS, NODES);
    }

    smax_partial<<<NGRAPH * SSPLIT, 256, 0, stream>>>((const float4*)x, gstart, gend, tptr, part);
    smax_combine<<<(NGRAPH * NCOLS + 255) / 256, 256, 0, stream>>>(part, reps);
}

// Round 7
// 2320.592 us; speedup vs baseline: 2.4613x; 1.4343x over previous
//
#include <hip/hip_runtime.h>
#include <math.h>

#define NODES   100000
#define EDGES   1600000
#define NGRAPH  64
#define DIN     128
#define DH      64
#define NLAYERS 12
#define NCOLS   ((NLAYERS + 1) * DH)   // 832
#define NC4     (NCOLS / 4)            // 208
#define SSPLIT  16
#define PROP_BLOCKS 1024
#define NBLK_SCAN ((NODES + 255) / 256)   // 391
#define TM 64                              // gemm tile rows

// ---------------- init ----------------
__global__ void zero_init(int* __restrict__ deg, int* __restrict__ gstart,
                          int* __restrict__ gend) {
    int i = blockIdx.x * blockDim.x + threadIdx.x;
    if (i < NODES) deg[i] = 0;
    if (i < NGRAPH) { gstart[i] = NODES; gend[i] = 0; }
}

__global__ void deg_kernel(const int* __restrict__ dst, int* __restrict__ deg) {
    int e = blockIdx.x * blockDim.x + threadIdx.x;
    if (e < EDGES) atomicAdd(&deg[dst[e]], 1);
}

// batch_index is SORTED -> boundaries give ranges, no atomics.
__global__ void range_kernel(const int* __restrict__ batch, int* __restrict__ gstart,
                             int* __restrict__ gend) {
    int n = blockIdx.x * blockDim.x + threadIdx.x;
    if (n >= NODES) return;
    int b = batch[n];
    if (n == 0) {
        gstart[b] = 0;
    } else {
        int pb = batch[n - 1];
        if (pb != b) { gstart[b] = n; gend[pb] = n; }
    }
    if (n == NODES - 1) gend[b] = NODES;
}

__global__ void dinv_kernel(const int* __restrict__ deg, float* __restrict__ dinv) {
    int n = blockIdx.x * blockDim.x + threadIdx.x;
    if (n < NODES) dinv[n] = 1.0f / sqrtf((float)deg[n] + 1.0f);
}

// ---------------- parallel scan: deg -> exclusive offs ----------------
__global__ void scan_part(const int* __restrict__ deg, int* __restrict__ bsum) {
    __shared__ int sh[256];
    int i = blockIdx.x * 256 + threadIdx.x;
    sh[threadIdx.x] = (i < NODES) ? deg[i] : 0;
    __syncthreads();
    for (int off = 128; off > 0; off >>= 1) {
        if (threadIdx.x < off) sh[threadIdx.x] += sh[threadIdx.x + off];
        __syncthreads();
    }
    if (threadIdx.x == 0) bsum[blockIdx.x] = sh[0];
}

__global__ void scan_top(const int* __restrict__ bsum, int* __restrict__ bpre,
                         int* __restrict__ offs) {
    __shared__ int sh[512];
    int t = threadIdx.x;
    int v = (t < NBLK_SCAN) ? bsum[t] : 0;
    sh[t] = v;
    __syncthreads();
    for (int off = 1; off < 512; off <<= 1) {
        int u = (t >= off) ? sh[t - off] : 0;
        __syncthreads();
        sh[t] += u;
        __syncthreads();
    }
    if (t < NBLK_SCAN) bpre[t] = sh[t] - v;   // exclusive block prefix
    if (t == NBLK_SCAN - 1) offs[NODES] = sh[t];
}

__global__ void scan_write(const int* __restrict__ deg, const int* __restrict__ bpre,
                           int* __restrict__ offs, int* __restrict__ cursor) {
    __shared__ int sh[256];
    int t = threadIdx.x;
    int i = blockIdx.x * 256 + t;
    int v = (i < NODES) ? deg[i] : 0;
    sh[t] = v;
    __syncthreads();
    for (int off = 1; off < 256; off <<= 1) {
        int u = (t >= off) ? sh[t - off] : 0;
        __syncthreads();
        sh[t] += u;
        __syncthreads();
    }
    if (i < NODES) {
        int ex = bpre[blockIdx.x] + sh[t] - v;
        offs[i] = ex; cursor[i] = ex;
    }
}

__global__ void fill_kernel(const int* __restrict__ src, const int* __restrict__ dst,
                            const float* __restrict__ dinv, int* __restrict__ cursor,
                            int* __restrict__ csr_src, float* __restrict__ csr_ew) {
    int e = blockIdx.x * blockDim.x + threadIdx.x;
    if (e < EDGES) {
        int s = src[e], d = dst[e];
        int pos = atomicAdd(&cursor[d], 1);
        csr_src[pos] = s;
        csr_ew[pos] = dinv[s] * dinv[d];
    }
}

// ---------------- tiled GEMM (+ fused graph-LN + LeakyReLU on input) ----------------
// 64-row tile. W[K][64] and transposed 64-col input half-tile in LDS.
// Each thread: acc[4][4], 2x ds_read_b128 + 16 FMA per k.
template <int K, bool DO_LN>
__global__ __launch_bounds__(256) void gemm_tiled(
    const float* __restrict__ in, int in_stride,
    const float* __restrict__ W, float* __restrict__ h,
    const float2* __restrict__ bp,
    const float* __restrict__ lnw, const float* __restrict__ lnb) {
    __shared__ float Wl[K][68];
    __shared__ float inT[64][68];     // [local k][row]
    __shared__ float afin[64], cfin[64];
    __shared__ double shs[4], shq[4];
    const int tid = threadIdx.x;
    const int r0 = blockIdx.x * TM;

    if (DO_LN) {
        double ls = 0.0, lq = 0.0;
        for (int i = tid; i < PROP_BLOCKS; i += 256) {
            float2 v = bp[i]; ls += (double)v.x; lq += (double)v.y;
        }
        for (int o = 32; o > 0; o >>= 1) { ls += __shfl_down(ls, o); lq += __shfl_down(lq, o); }
        int wwid = tid >> 6, lane = tid & 63;
        if (lane == 0) { shs[wwid] = ls; shq[wwid] = lq; }
        __syncthreads();
        if (tid < 64) {
            double tsum = shs[0] + shs[1] + shs[2] + shs[3];
            double tsq  = shq[0] + shq[1] + shq[2] + shq[3];
            double M = (double)NODES * 64.0;
            double mu = tsum / M;
            double var = tsq / M - mu * mu; if (var < 0.0) var = 0.0;
            float mean = (float)mu;
            float istd = (float)(1.0 / (sqrt(var) + 1e-5));
            float a = istd * lnw[tid];
            afin[tid] = a;
            cfin[tid] = lnb[tid] - mean * a;
        }
    }
    // stage W (float4 rows of 64 cols)
    for (int i = tid; i < K * 16; i += 256) {
        int k = i >> 4, c4 = (i & 15) * 4;
        float4 w4 = *(const float4*)&W[k * 64 + c4];
        *(float4*)&Wl[k][c4] = w4;
    }
    __syncthreads();

    const int tc = tid & 15;   // col group (4 cols)
    const int tr = tid >> 4;   // row group (4 rows)
    float acc[4][4] = {{0.f}};

    for (int k0 = 0; k0 < K; k0 += 64) {
        // stage transposed input half-tile with fused LN+leaky
        {
            int col = tid & 63;
            int rg = tid >> 6;
            float a = 1.f, c = 0.f;
            if (DO_LN) { a = afin[col]; c = cfin[col]; }
            for (int j = 0; j < 16; ++j) {
                int r = rg + 4 * j;
                int gr = r0 + r;
                float v = 0.f;
                if (gr < NODES) v = in[(size_t)gr * in_stride + k0 + col];
                if (DO_LN) { v = a * v + c; v = v > 0.f ? v : 0.01f * v; }
                inT[col][r] = v;
            }
        }
        __syncthreads();
#pragma unroll 4
        for (int kk = 0; kk < 64; ++kk) {
            float4 av = *(float4*)&inT[kk][tr * 4];
            float4 bv = *(float4*)&Wl[k0 + kk][tc * 4];
            acc[0][0] += av.x * bv.x; acc[0][1] += av.x * bv.y; acc[0][2] += av.x * bv.z; acc[0][3] += av.x * bv.w;
            acc[1][0] += av.y * bv.x; acc[1][1] += av.y * bv.y; acc[1][2] += av.y * bv.z; acc[1][3] += av.y * bv.w;
            acc[2][0] += av.z * bv.x; acc[2][1] += av.z * bv.y; acc[2][2] += av.z * bv.z; acc[2][3] += av.z * bv.w;
            acc[3][0] += av.w * bv.x; acc[3][1] += av.w * bv.y; acc[3][2] += av.w * bv.z; acc[3][3] += av.w * bv.w;
        }
        __syncthreads();
    }
    for (int i = 0; i < 4; ++i) {
        int gr = r0 + tr * 4 + i;
        if (gr < NODES) {
            float4 o = make_float4(acc[i][0], acc[i][1], acc[i][2], acc[i][3]);
            *(float4*)&h[(size_t)gr * 64 + tc * 4] = o;
        }
    }
}

// ---------------- propagate: out = segsum(h[src]*ew) + h*dinv^2 + b ----------------
// One node per WAVE: 16 chan-lanes (float4) x 4 edge slots in flight.
__global__ __launch_bounds__(256) void prop_kernel(
    const float4* __restrict__ h4, const float* __restrict__ dinv,
    const int* __restrict__ offs, const int* __restrict__ csr_src,
    const float* __restrict__ csr_ew, const float* __restrict__ bias,
    float* __restrict__ out /*stride NCOLS*/, float2* __restrict__ bp, int n_nodes) {
    const int lane = threadIdx.x & 63;
    const int sub  = lane & 15;      // channel group (4 channels)
    const int slot = lane >> 4;      // edge slot 0..3
    const int wwid = threadIdx.x >> 6;
    const int wid = blockIdx.x * 4 + wwid;
    const int nw = gridDim.x * 4;
    float4 b4 = ((const float4*)bias)[sub];
    float lsum = 0.f, lsq = 0.f;
    for (int n = wid; n < n_nodes; n += nw) {
        int s0 = offs[n], s1 = offs[n + 1];
        float4 acc = make_float4(0.f, 0.f, 0.f, 0.f);
        for (int idx = s0 + slot; idx < s1; idx += 4) {
            int s = csr_src[idx];
            float w = csr_ew[idx];
            float4 v = h4[(size_t)s * 16 + sub];
            acc.x += v.x * w; acc.y += v.y * w; acc.z += v.z * w; acc.w += v.w * w;
        }
        // reduce over the 4 edge slots (lane bits 4,5)
        acc.x += __shfl_xor(acc.x, 16); acc.y += __shfl_xor(acc.y, 16);
        acc.z += __shfl_xor(acc.z, 16); acc.w += __shfl_xor(acc.w, 16);
        acc.x += __shfl_xor(acc.x, 32); acc.y += __shfl_xor(acc.y, 32);
        acc.z += __shfl_xor(acc.z, 32); acc.w += __shfl_xor(acc.w, 32);
        if (slot == 0) {
            float dv = dinv[n];
            float dw = dv * dv;
            float4 hv = h4[(size_t)n * 16 + sub];
            acc.x += hv.x * dw + b4.x;
            acc.y += hv.y * dw + b4.y;
            acc.z += hv.z * dw + b4.z;
            acc.w += hv.w * dw + b4.w;
            ((float4*)(out + (size_t)n * NCOLS))[sub] = acc;
            lsum += acc.x + acc.y + acc.z + acc.w;
            lsq  += acc.x * acc.x + acc.y * acc.y + acc.z * acc.z + acc.w * acc.w;
        }
    }
    for (int o = 32; o > 0; o >>= 1) { lsum += __shfl_down(lsum, o); lsq += __shfl_down(lsq, o); }
    __shared__ float ss[4], sq[4];
    if (lane == 0) { ss[wwid] = lsum; sq[wwid] = lsq; }
    __syncthreads();
    if (threadIdx.x == 0) {
        float2 v; v.x = ss[0] + ss[1] + ss[2] + ss[3]; v.y = sq[0] + sq[1] + sq[2] + sq[3];
        bp[blockIdx.x] = v;
    }
}

// ---------------- softmax aggregation (two-stage online, float4) ----------------
#define ONLINE(comp)                                                     \
    {                                                                    \
        float y = v.comp * t;                                            \
        if (y > m.comp) {                                                \
            float sc = expf(m.comp - y);                                 \
            su.comp *= sc; ws.comp *= sc; m.comp = y;                    \
        }                                                                \
        float e = expf(y - m.comp);                                      \
        su.comp += e; ws.comp += e * v.comp;                             \
    }

__global__ __launch_bounds__(256) void smax_partial(
    const float4* __restrict__ x4, const int* __restrict__ gstart,
    const int* __restrict__ gend, const float* __restrict__ tptr,
    float* __restrict__ part) {
    int g = blockIdx.x / SSPLIT;
    int sp = blockIdx.x % SSPLIT;
    int c = threadIdx.x;           // float4 column group 0..207
    if (c >= NC4) return;
    float t = *tptr;
    int s0 = gstart[g], s1 = gend[g];
    if (s0 > s1) { s0 = 0; s1 = 0; }
    int cnt = s1 - s0;
    int per = (cnt + SSPLIT - 1) / SSPLIT;
    int a = s0 + sp * per;
    int bnd = a + per; if (bnd > s1) bnd = s1;
    float4 m  = make_float4(-3.4e38f, -3.4e38f, -3.4e38f, -3.4e38f);
    float4 su = make_float4(0.f, 0.f, 0.f, 0.f);
    float4 ws = make_float4(0.f, 0.f, 0.f, 0.f);
    for (int n = a; n < bnd; ++n) {
        float4 v = x4[(size_t)n * NC4 + c];
        ONLINE(x) ONLINE(y) ONLINE(z) ONLINE(w)
    }
    size_t base = ((size_t)g * SSPLIT + sp) * 3 * NCOLS;
    ((float4*)(part + base))[c] = m;
    ((float4*)(part + base + NCOLS))[c] = su;
    ((float4*)(part + base + 2 * NCOLS))[c] = ws;
}

__global__ void smax_combine(const float* __restrict__ part, float* __restrict__ reps) {
    int i = blockIdx.x * blockDim.x + threadIdx.x;
    if (i >= NGRAPH * NCOLS) return;
    int g = i / NCOLS, c = i % NCOLS;
    float M = -3.4e38f;
    for (int s = 0; s < SSPLIT; ++s) {
        float m = part[((size_t)g * SSPLIT + s) * 3 * NCOLS + c];
        if (m > M) M = m;
    }
    float su = 0.f, ws = 0.f;
    for (int s = 0; s < SSPLIT; ++s) {
        size_t o = ((size_t)g * SSPLIT + s) * 3 * NCOLS + c;
        float e = expf(part[o] - M);
        su += part[o + NCOLS] * e;
        ws += part[o + 2 * NCOLS] * e;
    }
    reps[i] = (su > 0.f) ? ws / su : 0.f;
}

// ---------------- launch ----------------
extern "C" void kernel_launch(void* const* d_in, const int* in_sizes, int n_in,
                              void* d_out, int out_size, void* d_ws, size_t ws_size,
                              hipStream_t stream) {
    const float* nf   = (const float*)d_in[0];
    const int*   ei   = (const int*)d_in[1];
    const int*   batch = (const int*)d_in[3];
    const float* W0   = (const float*)d_in[4];
    const float* b0   = (const float*)d_in[5];
    const float* lnw  = (const float*)d_in[6];
    const float* lnb  = (const float*)d_in[7];
    const float* Ws   = (const float*)d_in[8];
    const float* bs   = (const float*)d_in[9];
    const float* tptr = (const float*)d_in[10];

    const int* esrc = ei;
    const int* edst = ei + EDGES;

    float* reps = (float*)d_out;
    float* x = reps + (size_t)NGRAPH * NCOLS;  // x region lives directly in d_out

    char* p = (char*)d_ws;
    auto alloc = [&](size_t bytes) -> void* {
        void* r = (void*)p;
        p += (bytes + 255) & ~(size_t)255;
        return r;
    };
    int*    deg     = (int*)alloc(NODES * 4);
    int*    offs    = (int*)alloc((NODES + 1) * 4);
    int*    cursor  = (int*)alloc(NODES * 4);
    int*    gstart  = (int*)alloc(NGRAPH * 4);
    int*    gend    = (int*)alloc(NGRAPH * 4);
    float*  dinv    = (float*)alloc(NODES * 4);
    int*    csr_src = (int*)alloc(EDGES * 4);
    float*  csr_ew  = (float*)alloc(EDGES * 4);
    float*  h       = (float*)alloc((size_t)NODES * DH * 4);
    float2* bp      = (float2*)alloc((size_t)(NLAYERS + 1) * PROP_BLOCKS * sizeof(float2));
    float*  part    = (float*)alloc((size_t)NGRAPH * SSPLIT * 3 * NCOLS * 4);
    int*    bsum    = (int*)alloc(NBLK_SCAN * 4);
    int*    bpre    = (int*)alloc(NBLK_SCAN * 4);

    zero_init<<<(NODES + 255) / 256, 256, 0, stream>>>(deg, gstart, gend);
    deg_kernel<<<(EDGES + 255) / 256, 256, 0, stream>>>(edst, deg);
    range_kernel<<<(NODES + 255) / 256, 256, 0, stream>>>(batch, gstart, gend);
    dinv_kernel<<<(NODES + 255) / 256, 256, 0, stream>>>(deg, dinv);
    scan_part<<<NBLK_SCAN, 256, 0, stream>>>(deg, bsum);
    scan_top<<<1, 512, 0, stream>>>(bsum, bpre, offs);
    scan_write<<<NBLK_SCAN, 256, 0, stream>>>(deg, bpre, offs, cursor);
    fill_kernel<<<(EDGES + 255) / 256, 256, 0, stream>>>(esrc, edst, dinv, cursor, csr_src, csr_ew);

    const int GEMM_BLOCKS = (NODES + TM - 1) / TM;   // 1563
    gemm_tiled<DIN, false><<<GEMM_BLOCKS, 256, 0, stream>>>(nf, DIN, W0, h, nullptr, nullptr, nullptr);
    prop_kernel<<<PROP_BLOCKS, 256, 0, stream>>>((const float4*)h, dinv, offs, csr_src, csr_ew, b0,
                                                 x, bp, NODES);
    for (int i = 0; i < NLAYERS; ++i) {
        gemm_tiled<DH, true><<<GEMM_BLOCKS, 256, 0, stream>>>(
            x + (size_t)i * DH, NCOLS, Ws + (size_t)i * DH * DH, h,
            bp + (size_t)i * PROP_BLOCKS, lnw + (size_t)i * DH, lnb + (size_t)i * DH);
        prop_kernel<<<PROP_BLOCKS, 256, 0, stream>>>(
            (const float4*)h, dinv, offs, csr_src, csr_ew, bs + (size_t)i * DH,
            x + (size_t)(i + 1) * DH, bp + (size_t)(i + 1) * PROP_BLOCKS, NODES);
    }

    smax_partial<<<NGRAPH * SSPLIT, 256, 0, stream>>>((const float4*)x, gstart, gend, tptr, part);
    smax_combine<<<(NGRAPH * NCOLS + 255) / 256, 256, 0, stream>>>(part, reps);
}